// Round 10
// baseline (660.341 us; speedup 1.0000x reference)
//
#include <hip/hip_runtime.h>

#define NNODES 20000
#define FIN 64
#define HDIM 512
#define NEDGE 160000

typedef _Float16 f16;
typedef _Float16 f16x8 __attribute__((ext_vector_type(8)));
typedef _Float16 f16x4 __attribute__((ext_vector_type(4)));
typedef float f32x4 __attribute__((ext_vector_type(4)));

#define SLICE ((size_t)NNODES * HDIM)
#define HH ((size_t)HDIM * HDIM)

// ---------------------------------------------------------------- helpers
__device__ __forceinline__ void async_lds16(const void* g, void* lds_base) {
  __builtin_amdgcn_global_load_lds(
      (const __attribute__((address_space(1))) void*)g,
      (__attribute__((address_space(3))) void*)lds_base, 16, 0, 0);
}

// ---------------------------------------------------------------- fused prep
// blocks [0,313): zero deg
// [313,25313): cvt x -> f16
// [25313,25953): W_in [5][64][512] -> [5][512][64] f16
// [25953,27489): W1/W2 tiled transpose -> f16.
//   W1t slots p*HH ld512, p: 0=(0,0) 1=(0,1) 2=(0,3) 3=(0,4) 4=(1,1) 5=(1,4)
//   W2t: (0,0)->base0 ld512; (0,3)->base1 ld512; (0,1)->cat base2 ld1024 co0;
//        (0,4)->cat base2 ld1024 co512; (1,1)->cat base4 ld1024 co0;
//        (1,4)->cat base4 ld1024 co512
__global__ __launch_bounds__(256) void k_prep(
    const float* __restrict__ x, f16* __restrict__ xb,
    const float* __restrict__ Win, f16* __restrict__ Wint,
    const float* __restrict__ W1, const float* __restrict__ W2,
    f16* __restrict__ W1t, f16* __restrict__ W2t, int* __restrict__ deg) {
  __shared__ float t1[32][33], t2[32][33];
  int b = blockIdx.x;
  if (b < 313) {
    int i = b * 256 + threadIdx.x;
    if (i < 4 * NNODES) deg[i] = 0;
  } else if (b < 25313) {
    int i = (b - 313) * 256 + threadIdx.x;
    xb[i] = (f16)x[i];
  } else if (b < 25953) {
    int i = (b - 25313) * 256 + threadIdx.x;
    int t = i >> 15;
    int rem = i & 32767;
    int nn = rem >> 6;
    int kk = rem & 63;
    Wint[i] = (f16)Win[(size_t)t * 32768 + (size_t)kk * 512 + nn];
  } else {
    const int LT[6] = {0, 1, 3, 4, 7, 10};
    const int W2BASE[6] = {0, 2, 1, 2, 4, 4};   // in HH units
    const int W2LD[6] = {512, 1024, 512, 1024, 1024, 1024};
    const int W2CO[6] = {0, 0, 0, 512, 0, 512};
    int b2 = b - 25953;
    int p = b2 >> 8;
    int tile = b2 & 255;
    int bx = tile & 15;
    int by = tile >> 4;
    int tx = threadIdx.x & 31;
    int ty = threadIdx.x >> 5;  // 0..7
    size_t sbase = (size_t)LT[p] * HH;
    size_t dbase1 = (size_t)p * HH;
    size_t dbase2 = (size_t)W2BASE[p] * HH;
    int ld2 = W2LD[p], co2 = W2CO[p];
#pragma unroll
    for (int r = 0; r < 4; ++r) {
      int kk = bx * 32 + ty + r * 8;
      int nn = by * 32 + tx;
      t1[ty + r * 8][tx] = W1[sbase + (size_t)kk * 512 + nn];
      t2[ty + r * 8][tx] = W2[sbase + (size_t)kk * 512 + nn];
    }
    __syncthreads();
#pragma unroll
    for (int r = 0; r < 4; ++r) {
      int nn = by * 32 + ty + r * 8;
      int kk = bx * 32 + tx;
      W1t[dbase1 + (size_t)nn * 512 + kk] = (f16)t1[tx][ty + r * 8];
      W2t[dbase2 + (size_t)nn * ld2 + co2 + kk] = (f16)t2[tx][ty + r * 8];
    }
  }
}

// ---------------------------------------------------------------- CSR build
__global__ void k_hist(const int* __restrict__ edges, int* __restrict__ deg) {
  const int TMAP[4] = {0, 1, 3, 4};
  int c = blockIdx.y;
  int t = TMAP[c];
  int e = blockIdx.x * 256 + threadIdx.x;
  if (e < NEDGE) {
    int dst = edges[(size_t)t * 2 * NEDGE + NEDGE + e];
    atomicAdd(&deg[c * NNODES + dst], 1);
  }
}

__global__ void k_scan(const int* __restrict__ deg, int* __restrict__ offs,
                       int* __restrict__ cursor) {
  int c = blockIdx.x;
  const int* d = deg + (size_t)c * NNODES;
  int* o = offs + (size_t)c * NNODES;
  int* cu = cursor + (size_t)c * NNODES;
  __shared__ int sums[256];
  int tid = threadIdx.x;
  const int CH = 79;
  int start = tid * CH;
  int end = min(start + CH, NNODES);
  int s = 0;
  for (int i = start; i < end; ++i) s += d[i];
  sums[tid] = s;
  __syncthreads();
  for (int off = 1; off < 256; off <<= 1) {
    int v = (tid >= off) ? sums[tid - off] : 0;
    __syncthreads();
    sums[tid] += v;
    __syncthreads();
  }
  int run = sums[tid] - s;
  for (int i = start; i < end; ++i) {
    o[i] = run;
    cu[i] = run;
    run += d[i];
  }
}

__global__ void k_scatter(const int* __restrict__ edges, int* __restrict__ cursor,
                          int* __restrict__ csr) {
  const int TMAP[4] = {0, 1, 3, 4};
  int c = blockIdx.y;
  int t = TMAP[c];
  int e = blockIdx.x * 256 + threadIdx.x;
  if (e < NEDGE) {
    int src = edges[(size_t)t * 2 * NEDGE + e];
    int dst = edges[(size_t)t * 2 * NEDGE + NEDGE + e];
    int slot = atomicAdd(&cursor[c * NNODES + dst], 1);
    csr[(size_t)c * NEDGE + slot] = src;
  }
}

// Canonicalize CSR: in-place insertion sort of each row's src list, so the
// downstream accumulation order is identical every launch (atomic scatter
// order is timing-dependent).
__global__ void k_sort(const int* __restrict__ offs, const int* __restrict__ rend,
                       int* __restrict__ csr) {
  int c = blockIdx.y;
  int i = blockIdx.x * 256 + threadIdx.x;
  if (i >= NNODES) return;
  int* row = csr + (size_t)c * NEDGE;
  int s = offs[c * NNODES + i];
  int e = rend[c * NNODES + i];
  for (int j = s + 1; j < e; ++j) {
    int key = row[j];
    int k = j - 1;
    while (k >= s && row[k] > key) {
      row[k + 1] = row[k];
      --k;
    }
    row[k + 1] = key;
  }
}

// ---------------------------------------------------------------- aggregation
// Column-split: 2 waves per dst row, each covers a 256-col half (f16x4/lane).
struct AggSlot {
  const f16* dst;
  const f16* dst2;   // nullable: base = relu(dst+dst2)
  const f16* src1;
  const int* offs1;
  const int* rend1;
  const int* csr1;
  f16* out1;
  const f16* src2;   // nullable: second list sharing base
  const int* offs2;
  const int* rend2;
  const int* csr2;
  f16* out2;
};
struct AggBatch { AggSlot s[3]; };

__device__ __forceinline__ void agg_list(const f16* __restrict__ hs,
                                         const int* __restrict__ cs,
                                         int e, int e1, int col,
                                         const float* __restrict__ base,
                                         f16* __restrict__ outp) {
  float acc[4];
#pragma unroll
  for (int q = 0; q < 4; ++q) acc[q] = base[q];
  for (; e + 3 < e1; e += 4) {
    int s0 = cs[e], s1 = cs[e + 1], s2 = cs[e + 2], s3 = cs[e + 3];
    f16x4 u0 = *(const f16x4*)(hs + (size_t)s0 * HDIM + col);
    f16x4 u1 = *(const f16x4*)(hs + (size_t)s1 * HDIM + col);
    f16x4 u2 = *(const f16x4*)(hs + (size_t)s2 * HDIM + col);
    f16x4 u3 = *(const f16x4*)(hs + (size_t)s3 * HDIM + col);
#pragma unroll
    for (int q = 0; q < 4; ++q)
      acc[q] += ((float)u0[q] + (float)u1[q]) + ((float)u2[q] + (float)u3[q]);
  }
  for (; e < e1; ++e) {
    int s0 = cs[e];
    f16x4 u0 = *(const f16x4*)(hs + (size_t)s0 * HDIM + col);
#pragma unroll
    for (int q = 0; q < 4; ++q) acc[q] += (float)u0[q];
  }
  f16x4 o;
#pragma unroll
  for (int q = 0; q < 4; ++q) o[q] = (f16)acc[q];
  *(f16x4*)outp = o;
}

__global__ __launch_bounds__(256) void k_agg(AggBatch ab) {
  const AggSlot sl = ab.s[blockIdx.y];
  int w = threadIdx.x >> 6;
  int i = blockIdx.x * 2 + (w >> 1);          // dst row
  int lane = threadIdx.x & 63;
  int col = (w & 1) * 256 + lane * 4;         // column within row
  const size_t off = (size_t)i * HDIM + col;
  float base[4];
  f16x4 v = *(const f16x4*)(sl.dst + off);
  if (sl.dst2) {
    f16x4 v2 = *(const f16x4*)(sl.dst2 + off);
#pragma unroll
    for (int q = 0; q < 4; ++q) base[q] = fmaxf((float)v[q] + (float)v2[q], 0.f);
  } else {
#pragma unroll
    for (int q = 0; q < 4; ++q) base[q] = (float)v[q];
  }
  agg_list(sl.src1, sl.csr1, sl.offs1[i], sl.rend1[i], col, base, sl.out1 + off);
  if (sl.src2)
    agg_list(sl.src2, sl.csr2, sl.offs2[i], sl.rend2[i], col, base, sl.out2 + off);
}

// ---------------------------------------------------------------- GEMM (C = A @ Bt^T)
// Tile 128(M) x 128(N), BK=32, 256 threads = 4 waves (2x2, each 64x64, 4x4 frags).
// Single-buffer staging + __syncthreads() (m97 structure: every barrier drains
// vmcnt/lgkmcnt fully -> race-free & bit-deterministic; raw s_barrier dbuf in
// R8 raced LDS reuse at 4 blocks/CU). 4 blocks/CU (32KB LDS, acc=64 VGPR).
// Grid: (4 n-blocks, ceil(M/128), z). A [M,K] f16 (stride lda), Bt [512 or
// 1024-cat, K] f16 (stride K). flags: 1=relu. Out f16 via LDS-bounce (ldd).
struct GemmBatch {
  const f16* A[6];
  const f16* B[6];
  const float* bias[6];
  const float* bias2[6];
  void* D[6];
  int flags[6];
  int Kz[6];
  int lda[6];
  int ldd[6];
};

__global__ __launch_bounds__(256, 4) void k_gemm(GemmBatch gb, int M) {
  __shared__ __align__(16) char smem[32768];  // A: 8KB @0; B: 8KB @8192; epilogue tile reuses [0,17408)
  const int z = blockIdx.z;
  const f16* __restrict__ A = gb.A[z];
  const f16* __restrict__ Bt = gb.B[z];
  const int flags = gb.flags[z];
  const int K = gb.Kz[z];
  const int lda = gb.lda[z];
  const int ldd = gb.ldd[z];
  const int tid = threadIdx.x;
  const int lane = tid & 63;
  const int wave = tid >> 6;
  const int n0 = blockIdx.x * 128;
  const int m0 = blockIdx.y * 128;
  const int wm = wave & 1, wn = wave >> 1;
  const int fr = lane & 15, fq = lane >> 4;
  const int r0 = tid >> 2;         // staging row within 64-row half
  const int co = (tid & 3) * 8;    // staging col offset in elements

  const f16* gA0 = A + (size_t)min(m0 + r0, M - 1) * lda + co;
  const f16* gA1 = A + (size_t)min(m0 + 64 + r0, M - 1) * lda + co;
  const f16* gB0 = Bt + (size_t)(n0 + r0) * K + co;
  const f16* gB1 = Bt + (size_t)(n0 + 64 + r0) * K + co;

  f32x4 acc[4][4];
#pragma unroll
  for (int a = 0; a < 4; ++a)
#pragma unroll
    for (int b = 0; b < 4; ++b) acc[a][b] = (f32x4){0.f, 0.f, 0.f, 0.f};

  const int nb = K >> 5;
  for (int i = 0; i < nb; ++i) {
    const int kk = i << 5;
    async_lds16(gA0 + kk, smem + wave * 1024);
    async_lds16(gA1 + kk, smem + 4096 + wave * 1024);
    async_lds16(gB0 + kk, smem + 8192 + wave * 1024);
    async_lds16(gB1 + kk, smem + 12288 + wave * 1024);
    __syncthreads();   // drains vmcnt(0): staged tile visible to all waves
    const f16* lA = (const f16*)smem;
    const f16* lB = (const f16*)(smem + 8192);
    f16x8 af[4], bf[4];
#pragma unroll
    for (int t = 0; t < 4; ++t)
      af[t] = *(const f16x8*)&lA[(wm * 64 + t * 16 + fr) * 32 + fq * 8];
#pragma unroll
    for (int t = 0; t < 4; ++t)
      bf[t] = *(const f16x8*)&lB[(wn * 64 + t * 16 + fr) * 32 + fq * 8];
#pragma unroll
    for (int mt = 0; mt < 4; ++mt)
#pragma unroll
      for (int nt = 0; nt < 4; ++nt)
        acc[mt][nt] = __builtin_amdgcn_mfma_f32_16x16x32_f16(af[mt], bf[nt], acc[mt][nt], 0, 0, 0);
    __syncthreads();   // drains lgkmcnt(0): all reads done before next stage overwrites
  }

  const float* __restrict__ bias = gb.bias[z];
  const float* __restrict__ bias2 = gb.bias2[z];

  // f16 out via LDS bounce: 2 passes of 64 rows, padded stride 136 f16
  f16* tile = (f16*)smem;
#pragma unroll
  for (int pass = 0; pass < 2; ++pass) {
    if (wm == pass) {
#pragma unroll
      for (int nt = 0; nt < 4; ++nt) {
        const int cl = wn * 64 + nt * 16 + fr;
        float bv = bias[n0 + cl];
        if (bias2) bv += bias2[n0 + cl];
#pragma unroll
        for (int mt = 0; mt < 4; ++mt) {
#pragma unroll
          for (int r = 0; r < 4; ++r) {
            float v = acc[mt][nt][r] + bv;
            if (flags & 1) v = fmaxf(v, 0.f);
            tile[(mt * 16 + fq * 4 + r) * 136 + cl] = (f16)v;
          }
        }
      }
    }
    __syncthreads();
#pragma unroll
    for (int q = 0; q < 4; ++q) {
      int idx = q * 256 + tid;
      int row = idx >> 4;
      int c8 = idx & 15;
      int grow = m0 + pass * 64 + row;
      f16x8 val = *(const f16x8*)&tile[row * 136 + c8 * 8];
      if (grow < M)
        *(f16x8*)((f16*)gb.D[z] + (size_t)grow * ldd + n0 + c8 * 8) = val;
    }
    __syncthreads();
  }
}

// ---------------------------------------------------------------- head
// y = relu(o) @ W_out + b_out   (o f16 [20000,512])
__global__ __launch_bounds__(256) void k_head(const f16* __restrict__ o,
                                              const float* __restrict__ Wout,
                                              const float* __restrict__ bout,
                                              float* __restrict__ y) {
  int i = blockIdx.x * 4 + (threadIdx.x >> 6);
  int lane = threadIdx.x & 63;
  f16x8 a = *(const f16x8*)(o + (size_t)i * HDIM + lane * 8);
  const float4* w = (const float4*)(Wout + lane * 8);
  float4 w0 = w[0], w1 = w[1];
  float wv[8] = {w0.x, w0.y, w0.z, w0.w, w1.x, w1.y, w1.z, w1.w};
  float s = 0.f;
#pragma unroll
  for (int q = 0; q < 8; ++q)
    s += fmaxf((float)a[q], 0.f) * wv[q];
#pragma unroll
  for (int m = 32; m; m >>= 1) s += __shfl_xor(s, m, 64);
  if (lane == 0) y[i] = s + bout[0];
}

// ---------------------------------------------------------------- launch
extern "C" void kernel_launch(void* const* d_in, const int* in_sizes, int n_in,
                              void* d_out, int out_size, void* d_ws, size_t ws_size,
                              hipStream_t stream) {
  const float* x_all = (const float*)d_in[0];
  const float* W_in = (const float*)d_in[1];
  const float* b_in = (const float*)d_in[2];
  const float* W1 = (const float*)d_in[3];
  const float* b1 = (const float*)d_in[4];
  const float* W2 = (const float*)d_in[5];
  const float* b2 = (const float*)d_in[6];
  const float* W_out = (const float*)d_in[7];
  const float* b_out = (const float*)d_in[8];
  const int* edges = (const int*)d_in[9];

  // ---- workspace carve (~207 MB)
  char* p = (char*)d_ws;
  auto take = [&](size_t bytes) {
    char* r = p;
    p += (bytes + 255) & ~(size_t)255;
    return r;
  };
  f16* xb = (f16*)take((size_t)5 * NNODES * FIN * 2);
  f16* Wint = (f16*)take((size_t)5 * HDIM * FIN * 2);
  f16* W1t = (f16*)take((size_t)6 * HH * 2);
  f16* W2t = (f16*)take((size_t)6 * HH * 2);
  int* deg = (int*)take((size_t)4 * NNODES * 4);
  int* offs = (int*)take((size_t)4 * NNODES * 4);
  int* cursor = (int*)take((size_t)4 * NNODES * 4);
  int* csr = (int*)take((size_t)4 * NEDGE * 4);
  f16* pool = (f16*)take((size_t)9 * SLICE * 2);
  auto P = [&](int s) { return pool + (size_t)s * SLICE; };
  f16* Z0 = P(0);  // [20000][1024] spanning P0,P1 (also reused as Z1 at layer 1)

  // ---- prep (fused) + CSR (+ canonical sort for launch-determinism)
  k_prep<<<27489, 256, 0, stream>>>(x_all, xb, W_in, Wint, W1, W2, W1t, W2t, deg);
  k_hist<<<dim3(625, 4), 256, 0, stream>>>(edges, deg);
  k_scan<<<4, 256, 0, stream>>>(deg, offs, cursor);
  k_scatter<<<dim3(625, 4), 256, 0, stream>>>(edges, cursor, csr);
  k_sort<<<dim3(79, 4), 256, 0, stream>>>(offs, cursor, csr);

  // ---- input projection: h0 types {0..4} -> {P0..P4}
  {
    GemmBatch g{};
    for (int t = 0; t < 5; ++t) {
      g.A[t] = xb + (size_t)t * NNODES * FIN;
      g.B[t] = Wint + (size_t)t * HDIM * FIN;
      g.bias[t] = b_in + (size_t)t * HDIM;
      g.D[t] = P(t);
      g.flags[t] = 1;
      g.Kz[t] = FIN; g.lda[t] = FIN; g.ldd[t] = HDIM;
    }
    k_gemm<<<dim3(4, 157, 5), 256, 0, stream>>>(g, NNODES);
  }

  // ---- layer 0 aggregations:
  // slot0 (dst h0[0]=P0): t1 src P1 -> P5; t4 src P3 -> P6
  // slot1 (dst h0[1]=P1): t0 src P4 -> P7
  // slot2 (dst h0[3]=P3): t3 src P2 -> P8
  {
    AggBatch a{};
    a.s[0].dst = P(0);
    a.s[0].src1 = P(1); a.s[0].offs1 = offs + 1 * NNODES;
    a.s[0].rend1 = cursor + 1 * NNODES; a.s[0].csr1 = csr + (size_t)1 * NEDGE;
    a.s[0].out1 = P(5);
    a.s[0].src2 = P(3); a.s[0].offs2 = offs + 3 * NNODES;
    a.s[0].rend2 = cursor + 3 * NNODES; a.s[0].csr2 = csr + (size_t)3 * NEDGE;
    a.s[0].out2 = P(6);
    a.s[1].dst = P(1);
    a.s[1].src1 = P(4); a.s[1].offs1 = offs + 0 * NNODES;
    a.s[1].rend1 = cursor + 0 * NNODES; a.s[1].csr1 = csr + (size_t)0 * NEDGE;
    a.s[1].out1 = P(7);
    a.s[2].dst = P(3);
    a.s[2].src1 = P(2); a.s[2].offs1 = offs + 2 * NNODES;
    a.s[2].rend1 = cursor + 2 * NNODES; a.s[2].csr1 = csr + (size_t)2 * NEDGE;
    a.s[2].out1 = P(8);
    k_agg<<<dim3(10000, 3), 256, 0, stream>>>(a);
  }

  // ---- layer 0 MLP1 (z=4): t1: P5->Z0c0; t4: P6->Z0c512; t0: P7->P2; t3: P8->P3
  {
    GemmBatch g{};
    g.A[0] = P(5); g.B[0] = W1t + 1 * HH; g.bias[0] = b1 + 1 * HDIM;
    g.D[0] = Z0; g.flags[0] = 1; g.Kz[0] = 512; g.lda[0] = 512; g.ldd[0] = 1024;
    g.A[1] = P(6); g.B[1] = W1t + 3 * HH; g.bias[1] = b1 + 4 * HDIM;
    g.D[1] = Z0 + 512; g.flags[1] = 1; g.Kz[1] = 512; g.lda[1] = 512; g.ldd[1] = 1024;
    g.A[2] = P(7); g.B[2] = W1t + 0 * HH; g.bias[2] = b1 + 0 * HDIM;
    g.D[2] = P(2); g.flags[2] = 1; g.Kz[2] = 512; g.lda[2] = 512; g.ldd[2] = 512;
    g.A[3] = P(8); g.B[3] = W1t + 2 * HH; g.bias[3] = b1 + 3 * HDIM;
    g.D[3] = P(3); g.flags[3] = 1; g.Kz[3] = 512; g.lda[3] = 512; g.ldd[3] = 512;
    k_gemm<<<dim3(4, 157, 4), 256, 0, stream>>>(g, NNODES);
  }

  // ---- layer 0 MLP2 (z=3):
  // z0: h1_t0 = relu(Z0 @ cat[W2(0,1);W2(0,4)] + b2a+b2b) -> P4 (K=1024)
  // z1: h1_t1 = relu(P2 @ W2(0,0) + b2) -> P5
  // z2: h1_t3 = relu(P3 @ W2(0,3) + b2) -> P6
  {
    GemmBatch g{};
    g.A[0] = Z0; g.B[0] = W2t + 2 * HH; g.bias[0] = b2 + 1 * HDIM;
    g.bias2[0] = b2 + 4 * HDIM; g.D[0] = P(4);
    g.flags[0] = 1; g.Kz[0] = 1024; g.lda[0] = 1024; g.ldd[0] = 512;
    g.A[1] = P(2); g.B[1] = W2t + 0 * HH; g.bias[1] = b2 + 0 * HDIM;
    g.D[1] = P(5); g.flags[1] = 1; g.Kz[1] = 512; g.lda[1] = 512; g.ldd[1] = 512;
    g.A[2] = P(3); g.B[2] = W2t + 1 * HH; g.bias[2] = b2 + 3 * HDIM;
    g.D[2] = P(6); g.flags[2] = 1; g.Kz[2] = 512; g.lda[2] = 512; g.ldd[2] = 512;
    k_gemm<<<dim3(4, 157, 3), 256, 0, stream>>>(g, NNODES);
  }

  // ---- layer 1 aggregation: base = P4 (h1_t0); src P5 (t1 csr) -> P7; src P6 (t4 csr) -> P8
  {
    AggBatch a{};
    a.s[0].dst = P(4);
    a.s[0].src1 = P(5); a.s[0].offs1 = offs + 1 * NNODES;
    a.s[0].rend1 = cursor + 1 * NNODES; a.s[0].csr1 = csr + (size_t)1 * NEDGE;
    a.s[0].out1 = P(7);
    a.s[0].src2 = P(6); a.s[0].offs2 = offs + 3 * NNODES;
    a.s[0].rend2 = cursor + 3 * NNODES; a.s[0].csr2 = csr + (size_t)3 * NEDGE;
    a.s[0].out2 = P(8);
    k_agg<<<dim3(10000, 1), 256, 0, stream>>>(a);
  }

  // ---- layer 1 MLP1 (z=2): P7 -> Z1 col0; P8 -> Z1 col512   (Z1 = [P0|P1], Z0 dead)
  f16* Z1 = Z0;
  {
    GemmBatch g{};
    g.A[0] = P(7); g.B[0] = W1t + 4 * HH; g.bias[0] = b1 + 7 * HDIM;
    g.D[0] = Z1; g.flags[0] = 1; g.Kz[0] = 512; g.lda[0] = 512; g.ldd[0] = 1024;
    g.A[1] = P(8); g.B[1] = W1t + 5 * HH; g.bias[1] = b1 + 10 * HDIM;
    g.D[1] = Z1 + 512; g.flags[1] = 1; g.Kz[1] = 512; g.lda[1] = 512; g.ldd[1] = 1024;
    k_gemm<<<dim3(4, 157, 2), 256, 0, stream>>>(g, NNODES);
  }

  // ---- layer 1 MLP2 (z=1, K=1024 concat): o = Z1 @ cat[W2(1,1);W2(1,4)] + b2a+b2b -> P2 (f16)
  {
    GemmBatch g{};
    g.A[0] = Z1; g.B[0] = W2t + 4 * HH; g.bias[0] = b2 + 7 * HDIM;
    g.bias2[0] = b2 + 10 * HDIM; g.D[0] = P(2);
    g.flags[0] = 0; g.Kz[0] = 1024; g.lda[0] = 1024; g.ldd[0] = 512;
    k_gemm<<<dim3(4, 157, 1), 256, 0, stream>>>(g, NNODES);
  }

  // ---- head
  k_head<<<5000, 256, 0, stream>>>(P(2), W_out, b_out, (float*)d_out);
}

// Round 11
// 648.501 us; speedup vs baseline: 1.0183x; 1.0183x over previous
//
#include <hip/hip_runtime.h>

#define NNODES 20000
#define FIN 64
#define HDIM 512
#define NEDGE 160000

typedef _Float16 f16;
typedef _Float16 f16x8 __attribute__((ext_vector_type(8)));
typedef _Float16 f16x4 __attribute__((ext_vector_type(4)));
typedef float f32x4 __attribute__((ext_vector_type(4)));

#define SLICE ((size_t)NNODES * HDIM)
#define HH ((size_t)HDIM * HDIM)

// ---------------------------------------------------------------- helpers
__device__ __forceinline__ void async_lds16(const void* g, void* lds_base) {
  __builtin_amdgcn_global_load_lds(
      (const __attribute__((address_space(1))) void*)g,
      (__attribute__((address_space(3))) void*)lds_base, 16, 0, 0);
}

// ---------------------------------------------------------------- fused prep
// blocks [0,313): zero deg
// [313,25313): cvt x -> f16
// [25313,25953): W_in [5][64][512] -> [5][512][64] f16
// [25953,27489): W1/W2 tiled transpose -> f16.
//   W1t slots p*HH ld512, p: 0=(0,0) 1=(0,1) 2=(0,3) 3=(0,4) 4=(1,1) 5=(1,4)
//   W2t: (0,0)->base0 ld512; (0,3)->base1 ld512; (0,1)->cat base2 ld1024 co0;
//        (0,4)->cat base2 ld1024 co512; (1,1)->cat base4 ld1024 co0;
//        (1,4)->cat base4 ld1024 co512
__global__ __launch_bounds__(256) void k_prep(
    const float* __restrict__ x, f16* __restrict__ xb,
    const float* __restrict__ Win, f16* __restrict__ Wint,
    const float* __restrict__ W1, const float* __restrict__ W2,
    f16* __restrict__ W1t, f16* __restrict__ W2t, int* __restrict__ deg) {
  __shared__ float t1[32][33], t2[32][33];
  int b = blockIdx.x;
  if (b < 313) {
    int i = b * 256 + threadIdx.x;
    if (i < 4 * NNODES) deg[i] = 0;
  } else if (b < 25313) {
    int i = (b - 313) * 256 + threadIdx.x;
    xb[i] = (f16)x[i];
  } else if (b < 25953) {
    int i = (b - 25313) * 256 + threadIdx.x;
    int t = i >> 15;
    int rem = i & 32767;
    int nn = rem >> 6;
    int kk = rem & 63;
    Wint[i] = (f16)Win[(size_t)t * 32768 + (size_t)kk * 512 + nn];
  } else {
    const int LT[6] = {0, 1, 3, 4, 7, 10};
    const int W2BASE[6] = {0, 2, 1, 2, 4, 4};   // in HH units
    const int W2LD[6] = {512, 1024, 512, 1024, 1024, 1024};
    const int W2CO[6] = {0, 0, 0, 512, 0, 512};
    int b2 = b - 25953;
    int p = b2 >> 8;
    int tile = b2 & 255;
    int bx = tile & 15;
    int by = tile >> 4;
    int tx = threadIdx.x & 31;
    int ty = threadIdx.x >> 5;  // 0..7
    size_t sbase = (size_t)LT[p] * HH;
    size_t dbase1 = (size_t)p * HH;
    size_t dbase2 = (size_t)W2BASE[p] * HH;
    int ld2 = W2LD[p], co2 = W2CO[p];
#pragma unroll
    for (int r = 0; r < 4; ++r) {
      int kk = bx * 32 + ty + r * 8;
      int nn = by * 32 + tx;
      t1[ty + r * 8][tx] = W1[sbase + (size_t)kk * 512 + nn];
      t2[ty + r * 8][tx] = W2[sbase + (size_t)kk * 512 + nn];
    }
    __syncthreads();
#pragma unroll
    for (int r = 0; r < 4; ++r) {
      int nn = by * 32 + ty + r * 8;
      int kk = bx * 32 + tx;
      W1t[dbase1 + (size_t)nn * 512 + kk] = (f16)t1[tx][ty + r * 8];
      W2t[dbase2 + (size_t)nn * ld2 + co2 + kk] = (f16)t2[tx][ty + r * 8];
    }
  }
}

// ---------------------------------------------------------------- CSR build
__global__ void k_hist(const int* __restrict__ edges, int* __restrict__ deg) {
  const int TMAP[4] = {0, 1, 3, 4};
  int c = blockIdx.y;
  int t = TMAP[c];
  int e = blockIdx.x * 256 + threadIdx.x;
  if (e < NEDGE) {
    int dst = edges[(size_t)t * 2 * NEDGE + NEDGE + e];
    atomicAdd(&deg[c * NNODES + dst], 1);
  }
}

__global__ void k_scan(const int* __restrict__ deg, int* __restrict__ offs,
                       int* __restrict__ cursor) {
  int c = blockIdx.x;
  const int* d = deg + (size_t)c * NNODES;
  int* o = offs + (size_t)c * NNODES;
  int* cu = cursor + (size_t)c * NNODES;
  __shared__ int sums[256];
  int tid = threadIdx.x;
  const int CH = 79;
  int start = tid * CH;
  int end = min(start + CH, NNODES);
  int s = 0;
  for (int i = start; i < end; ++i) s += d[i];
  sums[tid] = s;
  __syncthreads();
  for (int off = 1; off < 256; off <<= 1) {
    int v = (tid >= off) ? sums[tid - off] : 0;
    __syncthreads();
    sums[tid] += v;
    __syncthreads();
  }
  int run = sums[tid] - s;
  for (int i = start; i < end; ++i) {
    o[i] = run;
    cu[i] = run;
    run += d[i];
  }
}

__global__ void k_scatter(const int* __restrict__ edges, int* __restrict__ cursor,
                          int* __restrict__ csr) {
  const int TMAP[4] = {0, 1, 3, 4};
  int c = blockIdx.y;
  int t = TMAP[c];
  int e = blockIdx.x * 256 + threadIdx.x;
  if (e < NEDGE) {
    int src = edges[(size_t)t * 2 * NEDGE + e];
    int dst = edges[(size_t)t * 2 * NEDGE + NEDGE + e];
    int slot = atomicAdd(&cursor[c * NNODES + dst], 1);
    csr[(size_t)c * NEDGE + slot] = src;
  }
}

// Canonicalize CSR: in-place insertion sort of each row's src list, so the
// downstream accumulation order is identical every launch (atomic scatter
// order is timing-dependent).
__global__ void k_sort(const int* __restrict__ offs, const int* __restrict__ rend,
                       int* __restrict__ csr) {
  int c = blockIdx.y;
  int i = blockIdx.x * 256 + threadIdx.x;
  if (i >= NNODES) return;
  int* row = csr + (size_t)c * NEDGE;
  int s = offs[c * NNODES + i];
  int e = rend[c * NNODES + i];
  for (int j = s + 1; j < e; ++j) {
    int key = row[j];
    int k = j - 1;
    while (k >= s && row[k] > key) {
      row[k + 1] = row[k];
      --k;
    }
    row[k + 1] = key;
  }
}

// ---------------------------------------------------------------- aggregation
// Column-split: 2 waves per dst row, each covers a 256-col half (f16x4/lane).
struct AggSlot {
  const f16* dst;
  const f16* dst2;   // nullable: base = relu(dst+dst2)
  const f16* src1;
  const int* offs1;
  const int* rend1;
  const int* csr1;
  f16* out1;
  const f16* src2;   // nullable: second list sharing base
  const int* offs2;
  const int* rend2;
  const int* csr2;
  f16* out2;
};
struct AggBatch { AggSlot s[3]; };

__device__ __forceinline__ void agg_list(const f16* __restrict__ hs,
                                         const int* __restrict__ cs,
                                         int e, int e1, int col,
                                         const float* __restrict__ base,
                                         f16* __restrict__ outp) {
  float acc[4];
#pragma unroll
  for (int q = 0; q < 4; ++q) acc[q] = base[q];
  for (; e + 3 < e1; e += 4) {
    int s0 = cs[e], s1 = cs[e + 1], s2 = cs[e + 2], s3 = cs[e + 3];
    f16x4 u0 = *(const f16x4*)(hs + (size_t)s0 * HDIM + col);
    f16x4 u1 = *(const f16x4*)(hs + (size_t)s1 * HDIM + col);
    f16x4 u2 = *(const f16x4*)(hs + (size_t)s2 * HDIM + col);
    f16x4 u3 = *(const f16x4*)(hs + (size_t)s3 * HDIM + col);
#pragma unroll
    for (int q = 0; q < 4; ++q)
      acc[q] += ((float)u0[q] + (float)u1[q]) + ((float)u2[q] + (float)u3[q]);
  }
  for (; e < e1; ++e) {
    int s0 = cs[e];
    f16x4 u0 = *(const f16x4*)(hs + (size_t)s0 * HDIM + col);
#pragma unroll
    for (int q = 0; q < 4; ++q) acc[q] += (float)u0[q];
  }
  f16x4 o;
#pragma unroll
  for (int q = 0; q < 4; ++q) o[q] = (f16)acc[q];
  *(f16x4*)outp = o;
}

__global__ __launch_bounds__(256) void k_agg(AggBatch ab) {
  const AggSlot sl = ab.s[blockIdx.y];
  int w = threadIdx.x >> 6;
  int i = blockIdx.x * 2 + (w >> 1);          // dst row
  int lane = threadIdx.x & 63;
  int col = (w & 1) * 256 + lane * 4;         // column within row
  const size_t off = (size_t)i * HDIM + col;
  float base[4];
  f16x4 v = *(const f16x4*)(sl.dst + off);
  if (sl.dst2) {
    f16x4 v2 = *(const f16x4*)(sl.dst2 + off);
#pragma unroll
    for (int q = 0; q < 4; ++q) base[q] = fmaxf((float)v[q] + (float)v2[q], 0.f);
  } else {
#pragma unroll
    for (int q = 0; q < 4; ++q) base[q] = (float)v[q];
  }
  agg_list(sl.src1, sl.csr1, sl.offs1[i], sl.rend1[i], col, base, sl.out1 + off);
  if (sl.src2)
    agg_list(sl.src2, sl.csr2, sl.offs2[i], sl.rend2[i], col, base, sl.out2 + off);
}

// ---------------------------------------------------------------- GEMM (C = A @ Bt^T)
// Tile 128(M) x 128(N), BK=32, 256 threads = 4 waves (2x2, each 64x64, 4x4 frags).
// Deterministic double-buffer: ONE __syncthreads() per K-iter, prefetch of the
// next tile issued right AFTER the barrier (into the other buffer) so the DMA
// overlaps this iter's ds_read+MFMA. __syncthreads drains vmcnt+lgkmcnt per
// wave, so buffer reuse is race-free (unlike R8's raw s_barrier dbuf which
// raced at 4 blocks/CU). 4 blocks/CU (32KB LDS, acc=64 VGPR).
// Grid: (4 n-blocks, ceil(M/128), z). A [M,K] f16 (stride lda), Bt [512 or
// 1024-cat, K] f16 (stride K). flags: 1=relu. Out f16 via LDS-bounce (ldd).
struct GemmBatch {
  const f16* A[6];
  const f16* B[6];
  const float* bias[6];
  const float* bias2[6];
  void* D[6];
  int flags[6];
  int Kz[6];
  int lda[6];
  int ldd[6];
};

__global__ __launch_bounds__(256, 4) void k_gemm(GemmBatch gb, int M) {
  __shared__ __align__(16) char smem[32768];  // A: 2x8KB @0; B: 2x8KB @16384; epilogue reuses [0,17408)
  const int z = blockIdx.z;
  const f16* __restrict__ A = gb.A[z];
  const f16* __restrict__ Bt = gb.B[z];
  const int flags = gb.flags[z];
  const int K = gb.Kz[z];
  const int lda = gb.lda[z];
  const int ldd = gb.ldd[z];
  const int tid = threadIdx.x;
  const int lane = tid & 63;
  const int wave = tid >> 6;
  const int n0 = blockIdx.x * 128;
  const int m0 = blockIdx.y * 128;
  const int wm = wave & 1, wn = wave >> 1;
  const int fr = lane & 15, fq = lane >> 4;
  const int r0 = tid >> 2;         // staging row within 64-row half
  const int co = (tid & 3) * 8;    // staging col offset in elements

  const f16* gA0 = A + (size_t)min(m0 + r0, M - 1) * lda + co;
  const f16* gA1 = A + (size_t)min(m0 + 64 + r0, M - 1) * lda + co;
  const f16* gB0 = Bt + (size_t)(n0 + r0) * K + co;
  const f16* gB1 = Bt + (size_t)(n0 + 64 + r0) * K + co;

  f32x4 acc[4][4];
#pragma unroll
  for (int a = 0; a < 4; ++a)
#pragma unroll
    for (int b = 0; b < 4; ++b) acc[a][b] = (f32x4){0.f, 0.f, 0.f, 0.f};

  auto stage = [&](int b, int kk) {
    char* bufA = smem + b * 8192;
    char* bufB = smem + 16384 + b * 8192;
    async_lds16(gA0 + kk, bufA + wave * 1024);
    async_lds16(gA1 + kk, bufA + 4096 + wave * 1024);
    async_lds16(gB0 + kk, bufB + wave * 1024);
    async_lds16(gB1 + kk, bufB + 4096 + wave * 1024);
  };

  const int nb = K >> 5;
  stage(0, 0);
  for (int i = 0; i < nb; ++i) {
    const int cur = i & 1;
    // Drains this wave's outstanding DMA (buffer `cur` now complete) and all
    // prior ds_reads (buffer `cur^1` now free) before anyone re-stages it.
    __syncthreads();
    if (i + 1 < nb) stage(cur ^ 1, (i + 1) << 5);  // DMA overlaps compute below
    const f16* lA = (const f16*)(smem + cur * 8192);
    const f16* lB = (const f16*)(smem + 16384 + cur * 8192);
    f16x8 af[4], bf[4];
#pragma unroll
    for (int t = 0; t < 4; ++t)
      af[t] = *(const f16x8*)&lA[(wm * 64 + t * 16 + fr) * 32 + fq * 8];
#pragma unroll
    for (int t = 0; t < 4; ++t)
      bf[t] = *(const f16x8*)&lB[(wn * 64 + t * 16 + fr) * 32 + fq * 8];
#pragma unroll
    for (int mt = 0; mt < 4; ++mt)
#pragma unroll
      for (int nt = 0; nt < 4; ++nt)
        acc[mt][nt] = __builtin_amdgcn_mfma_f32_16x16x32_f16(af[mt], bf[nt], acc[mt][nt], 0, 0, 0);
  }
  __syncthreads();  // all LDS reads done before epilogue reuses the buffers

  const float* __restrict__ bias = gb.bias[z];
  const float* __restrict__ bias2 = gb.bias2[z];

  // f16 out via LDS bounce: 2 passes of 64 rows, padded stride 136 f16
  f16* tile = (f16*)smem;
#pragma unroll
  for (int pass = 0; pass < 2; ++pass) {
    if (wm == pass) {
#pragma unroll
      for (int nt = 0; nt < 4; ++nt) {
        const int cl = wn * 64 + nt * 16 + fr;
        float bv = bias[n0 + cl];
        if (bias2) bv += bias2[n0 + cl];
#pragma unroll
        for (int mt = 0; mt < 4; ++mt) {
#pragma unroll
          for (int r = 0; r < 4; ++r) {
            float v = acc[mt][nt][r] + bv;
            if (flags & 1) v = fmaxf(v, 0.f);
            tile[(mt * 16 + fq * 4 + r) * 136 + cl] = (f16)v;
          }
        }
      }
    }
    __syncthreads();
#pragma unroll
    for (int q = 0; q < 4; ++q) {
      int idx = q * 256 + tid;
      int row = idx >> 4;
      int c8 = idx & 15;
      int grow = m0 + pass * 64 + row;
      f16x8 val = *(const f16x8*)&tile[row * 136 + c8 * 8];
      if (grow < M)
        *(f16x8*)((f16*)gb.D[z] + (size_t)grow * ldd + n0 + c8 * 8) = val;
    }
    __syncthreads();
  }
}

// ---------------------------------------------------------------- head
// y = relu(o) @ W_out + b_out   (o f16 [20000,512])
__global__ __launch_bounds__(256) void k_head(const f16* __restrict__ o,
                                              const float* __restrict__ Wout,
                                              const float* __restrict__ bout,
                                              float* __restrict__ y) {
  int i = blockIdx.x * 4 + (threadIdx.x >> 6);
  int lane = threadIdx.x & 63;
  f16x8 a = *(const f16x8*)(o + (size_t)i * HDIM + lane * 8);
  const float4* w = (const float4*)(Wout + lane * 8);
  float4 w0 = w[0], w1 = w[1];
  float wv[8] = {w0.x, w0.y, w0.z, w0.w, w1.x, w1.y, w1.z, w1.w};
  float s = 0.f;
#pragma unroll
  for (int q = 0; q < 8; ++q)
    s += fmaxf((float)a[q], 0.f) * wv[q];
#pragma unroll
  for (int m = 32; m; m >>= 1) s += __shfl_xor(s, m, 64);
  if (lane == 0) y[i] = s + bout[0];
}

// ---------------------------------------------------------------- launch
extern "C" void kernel_launch(void* const* d_in, const int* in_sizes, int n_in,
                              void* d_out, int out_size, void* d_ws, size_t ws_size,
                              hipStream_t stream) {
  const float* x_all = (const float*)d_in[0];
  const float* W_in = (const float*)d_in[1];
  const float* b_in = (const float*)d_in[2];
  const float* W1 = (const float*)d_in[3];
  const float* b1 = (const float*)d_in[4];
  const float* W2 = (const float*)d_in[5];
  const float* b2 = (const float*)d_in[6];
  const float* W_out = (const float*)d_in[7];
  const float* b_out = (const float*)d_in[8];
  const int* edges = (const int*)d_in[9];

  // ---- workspace carve (~207 MB)
  char* p = (char*)d_ws;
  auto take = [&](size_t bytes) {
    char* r = p;
    p += (bytes + 255) & ~(size_t)255;
    return r;
  };
  f16* xb = (f16*)take((size_t)5 * NNODES * FIN * 2);
  f16* Wint = (f16*)take((size_t)5 * HDIM * FIN * 2);
  f16* W1t = (f16*)take((size_t)6 * HH * 2);
  f16* W2t = (f16*)take((size_t)6 * HH * 2);
  int* deg = (int*)take((size_t)4 * NNODES * 4);
  int* offs = (int*)take((size_t)4 * NNODES * 4);
  int* cursor = (int*)take((size_t)4 * NNODES * 4);
  int* csr = (int*)take((size_t)4 * NEDGE * 4);
  f16* pool = (f16*)take((size_t)9 * SLICE * 2);
  auto P = [&](int s) { return pool + (size_t)s * SLICE; };
  f16* Z0 = P(0);  // [20000][1024] spanning P0,P1 (also reused as Z1 at layer 1)

  // ---- prep (fused) + CSR (+ canonical sort for launch-determinism)
  k_prep<<<27489, 256, 0, stream>>>(x_all, xb, W_in, Wint, W1, W2, W1t, W2t, deg);
  k_hist<<<dim3(625, 4), 256, 0, stream>>>(edges, deg);
  k_scan<<<4, 256, 0, stream>>>(deg, offs, cursor);
  k_scatter<<<dim3(625, 4), 256, 0, stream>>>(edges, cursor, csr);
  k_sort<<<dim3(79, 4), 256, 0, stream>>>(offs, cursor, csr);

  // ---- input projection: h0 types {0..4} -> {P0..P4}
  {
    GemmBatch g{};
    for (int t = 0; t < 5; ++t) {
      g.A[t] = xb + (size_t)t * NNODES * FIN;
      g.B[t] = Wint + (size_t)t * HDIM * FIN;
      g.bias[t] = b_in + (size_t)t * HDIM;
      g.D[t] = P(t);
      g.flags[t] = 1;
      g.Kz[t] = FIN; g.lda[t] = FIN; g.ldd[t] = HDIM;
    }
    k_gemm<<<dim3(4, 157, 5), 256, 0, stream>>>(g, NNODES);
  }

  // ---- layer 0 aggregations:
  // slot0 (dst h0[0]=P0): t1 src P1 -> P5; t4 src P3 -> P6
  // slot1 (dst h0[1]=P1): t0 src P4 -> P7
  // slot2 (dst h0[3]=P3): t3 src P2 -> P8
  {
    AggBatch a{};
    a.s[0].dst = P(0);
    a.s[0].src1 = P(1); a.s[0].offs1 = offs + 1 * NNODES;
    a.s[0].rend1 = cursor + 1 * NNODES; a.s[0].csr1 = csr + (size_t)1 * NEDGE;
    a.s[0].out1 = P(5);
    a.s[0].src2 = P(3); a.s[0].offs2 = offs + 3 * NNODES;
    a.s[0].rend2 = cursor + 3 * NNODES; a.s[0].csr2 = csr + (size_t)3 * NEDGE;
    a.s[0].out2 = P(6);
    a.s[1].dst = P(1);
    a.s[1].src1 = P(4); a.s[1].offs1 = offs + 0 * NNODES;
    a.s[1].rend1 = cursor + 0 * NNODES; a.s[1].csr1 = csr + (size_t)0 * NEDGE;
    a.s[1].out1 = P(7);
    a.s[2].dst = P(3);
    a.s[2].src1 = P(2); a.s[2].offs1 = offs + 2 * NNODES;
    a.s[2].rend1 = cursor + 2 * NNODES; a.s[2].csr1 = csr + (size_t)2 * NEDGE;
    a.s[2].out1 = P(8);
    k_agg<<<dim3(10000, 3), 256, 0, stream>>>(a);
  }

  // ---- layer 0 MLP1 (z=4): t1: P5->Z0c0; t4: P6->Z0c512; t0: P7->P2; t3: P8->P3
  {
    GemmBatch g{};
    g.A[0] = P(5); g.B[0] = W1t + 1 * HH; g.bias[0] = b1 + 1 * HDIM;
    g.D[0] = Z0; g.flags[0] = 1; g.Kz[0] = 512; g.lda[0] = 512; g.ldd[0] = 1024;
    g.A[1] = P(6); g.B[1] = W1t + 3 * HH; g.bias[1] = b1 + 4 * HDIM;
    g.D[1] = Z0 + 512; g.flags[1] = 1; g.Kz[1] = 512; g.lda[1] = 512; g.ldd[1] = 1024;
    g.A[2] = P(7); g.B[2] = W1t + 0 * HH; g.bias[2] = b1 + 0 * HDIM;
    g.D[2] = P(2); g.flags[2] = 1; g.Kz[2] = 512; g.lda[2] = 512; g.ldd[2] = 512;
    g.A[3] = P(8); g.B[3] = W1t + 2 * HH; g.bias[3] = b1 + 3 * HDIM;
    g.D[3] = P(3); g.flags[3] = 1; g.Kz[3] = 512; g.lda[3] = 512; g.ldd[3] = 512;
    k_gemm<<<dim3(4, 157, 4), 256, 0, stream>>>(g, NNODES);
  }

  // ---- layer 0 MLP2 (z=3):
  // z0: h1_t0 = relu(Z0 @ cat[W2(0,1);W2(0,4)] + b2a+b2b) -> P4 (K=1024)
  // z1: h1_t1 = relu(P2 @ W2(0,0) + b2) -> P5
  // z2: h1_t3 = relu(P3 @ W2(0,3) + b2) -> P6
  {
    GemmBatch g{};
    g.A[0] = Z0; g.B[0] = W2t + 2 * HH; g.bias[0] = b2 + 1 * HDIM;
    g.bias2[0] = b2 + 4 * HDIM; g.D[0] = P(4);
    g.flags[0] = 1; g.Kz[0] = 1024; g.lda[0] = 1024; g.ldd[0] = 512;
    g.A[1] = P(2); g.B[1] = W2t + 0 * HH; g.bias[1] = b2 + 0 * HDIM;
    g.D[1] = P(5); g.flags[1] = 1; g.Kz[1] = 512; g.lda[1] = 512; g.ldd[1] = 512;
    g.A[2] = P(3); g.B[2] = W2t + 1 * HH; g.bias[2] = b2 + 3 * HDIM;
    g.D[2] = P(6); g.flags[2] = 1; g.Kz[2] = 512; g.lda[2] = 512; g.ldd[2] = 512;
    k_gemm<<<dim3(4, 157, 3), 256, 0, stream>>>(g, NNODES);
  }

  // ---- layer 1 aggregation: base = P4 (h1_t0); src P5 (t1 csr) -> P7; src P6 (t4 csr) -> P8
  {
    AggBatch a{};
    a.s[0].dst = P(4);
    a.s[0].src1 = P(5); a.s[0].offs1 = offs + 1 * NNODES;
    a.s[0].rend1 = cursor + 1 * NNODES; a.s[0].csr1 = csr + (size_t)1 * NEDGE;
    a.s[0].out1 = P(7);
    a.s[0].src2 = P(6); a.s[0].offs2 = offs + 3 * NNODES;
    a.s[0].rend2 = cursor + 3 * NNODES; a.s[0].csr2 = csr + (size_t)3 * NEDGE;
    a.s[0].out2 = P(8);
    k_agg<<<dim3(10000, 1), 256, 0, stream>>>(a);
  }

  // ---- layer 1 MLP1 (z=2): P7 -> Z1 col0; P8 -> Z1 col512   (Z1 = [P0|P1], Z0 dead)
  f16* Z1 = Z0;
  {
    GemmBatch g{};
    g.A[0] = P(7); g.B[0] = W1t + 4 * HH; g.bias[0] = b1 + 7 * HDIM;
    g.D[0] = Z1; g.flags[0] = 1; g.Kz[0] = 512; g.lda[0] = 512; g.ldd[0] = 1024;
    g.A[1] = P(8); g.B[1] = W1t + 5 * HH; g.bias[1] = b1 + 10 * HDIM;
    g.D[1] = Z1 + 512; g.flags[1] = 1; g.Kz[1] = 512; g.lda[1] = 512; g.ldd[1] = 1024;
    k_gemm<<<dim3(4, 157, 2), 256, 0, stream>>>(g, NNODES);
  }

  // ---- layer 1 MLP2 (z=1, K=1024 concat): o = Z1 @ cat[W2(1,1);W2(1,4)] + b2a+b2b -> P2 (f16)
  {
    GemmBatch g{};
    g.A[0] = Z1; g.B[0] = W2t + 4 * HH; g.bias[0] = b2 + 7 * HDIM;
    g.bias2[0] = b2 + 10 * HDIM; g.D[0] = P(2);
    g.flags[0] = 0; g.Kz[0] = 1024; g.lda[0] = 1024; g.ldd[0] = 512;
    k_gemm<<<dim3(4, 157, 1), 256, 0, stream>>>(g, NNODES);
  }

  // ---- head
  k_head<<<5000, 256, 0, stream>>>(P(2), W_out, b_out, (float*)d_out);
}

// Round 12
// 618.136 us; speedup vs baseline: 1.0683x; 1.0491x over previous
//
#include <hip/hip_runtime.h>

#define NNODES 20000
#define FIN 64
#define HDIM 512
#define NEDGE 160000

typedef _Float16 f16;
typedef _Float16 f16x8 __attribute__((ext_vector_type(8)));
typedef _Float16 f16x4 __attribute__((ext_vector_type(4)));
typedef float f32x4 __attribute__((ext_vector_type(4)));

#define SLICE ((size_t)NNODES * HDIM)
#define HH ((size_t)HDIM * HDIM)

// ---------------------------------------------------------------- helpers
__device__ __forceinline__ void async_lds16(const void* g, void* lds_base) {
  __builtin_amdgcn_global_load_lds(
      (const __attribute__((address_space(1))) void*)g,
      (__attribute__((address_space(3))) void*)lds_base, 16, 0, 0);
}

// ---------------------------------------------------------------- fused prep
// blocks [0,313): zero deg
// [313,25313): cvt x -> f16
// [25313,25953): W_in [5][64][512] -> [5][512][64] f16
// [25953,27489): W1/W2 tiled transpose -> f16.
//   W1t slots p*HH ld512, p: 0=(0,0) 1=(0,1) 2=(0,3) 3=(0,4) 4=(1,1) 5=(1,4)
//   W2t: (0,0)->base0 ld512; (0,3)->base1 ld512; (0,1)->cat base2 ld1024 co0;
//        (0,4)->cat base2 ld1024 co512; (1,1)->cat base4 ld1024 co0;
//        (1,4)->cat base4 ld1024 co512
__global__ __launch_bounds__(256) void k_prep(
    const float* __restrict__ x, f16* __restrict__ xb,
    const float* __restrict__ Win, f16* __restrict__ Wint,
    const float* __restrict__ W1, const float* __restrict__ W2,
    f16* __restrict__ W1t, f16* __restrict__ W2t, int* __restrict__ deg) {
  __shared__ float t1[32][33], t2[32][33];
  int b = blockIdx.x;
  if (b < 313) {
    int i = b * 256 + threadIdx.x;
    if (i < 4 * NNODES) deg[i] = 0;
  } else if (b < 25313) {
    int i = (b - 313) * 256 + threadIdx.x;
    xb[i] = (f16)x[i];
  } else if (b < 25953) {
    int i = (b - 25313) * 256 + threadIdx.x;
    int t = i >> 15;
    int rem = i & 32767;
    int nn = rem >> 6;
    int kk = rem & 63;
    Wint[i] = (f16)Win[(size_t)t * 32768 + (size_t)kk * 512 + nn];
  } else {
    const int LT[6] = {0, 1, 3, 4, 7, 10};
    const int W2BASE[6] = {0, 2, 1, 2, 4, 4};   // in HH units
    const int W2LD[6] = {512, 1024, 512, 1024, 1024, 1024};
    const int W2CO[6] = {0, 0, 0, 512, 0, 512};
    int b2 = b - 25953;
    int p = b2 >> 8;
    int tile = b2 & 255;
    int bx = tile & 15;
    int by = tile >> 4;
    int tx = threadIdx.x & 31;
    int ty = threadIdx.x >> 5;  // 0..7
    size_t sbase = (size_t)LT[p] * HH;
    size_t dbase1 = (size_t)p * HH;
    size_t dbase2 = (size_t)W2BASE[p] * HH;
    int ld2 = W2LD[p], co2 = W2CO[p];
#pragma unroll
    for (int r = 0; r < 4; ++r) {
      int kk = bx * 32 + ty + r * 8;
      int nn = by * 32 + tx;
      t1[ty + r * 8][tx] = W1[sbase + (size_t)kk * 512 + nn];
      t2[ty + r * 8][tx] = W2[sbase + (size_t)kk * 512 + nn];
    }
    __syncthreads();
#pragma unroll
    for (int r = 0; r < 4; ++r) {
      int nn = by * 32 + ty + r * 8;
      int kk = bx * 32 + tx;
      W1t[dbase1 + (size_t)nn * 512 + kk] = (f16)t1[tx][ty + r * 8];
      W2t[dbase2 + (size_t)nn * ld2 + co2 + kk] = (f16)t2[tx][ty + r * 8];
    }
  }
}

// ---------------------------------------------------------------- CSR build
__global__ void k_hist(const int* __restrict__ edges, int* __restrict__ deg) {
  const int TMAP[4] = {0, 1, 3, 4};
  int c = blockIdx.y;
  int t = TMAP[c];
  int e = blockIdx.x * 256 + threadIdx.x;
  if (e < NEDGE) {
    int dst = edges[(size_t)t * 2 * NEDGE + NEDGE + e];
    atomicAdd(&deg[c * NNODES + dst], 1);
  }
}

__global__ void k_scan(const int* __restrict__ deg, int* __restrict__ offs,
                       int* __restrict__ cursor) {
  int c = blockIdx.x;
  const int* d = deg + (size_t)c * NNODES;
  int* o = offs + (size_t)c * NNODES;
  int* cu = cursor + (size_t)c * NNODES;
  __shared__ int sums[256];
  int tid = threadIdx.x;
  const int CH = 79;
  int start = tid * CH;
  int end = min(start + CH, NNODES);
  int s = 0;
  for (int i = start; i < end; ++i) s += d[i];
  sums[tid] = s;
  __syncthreads();
  for (int off = 1; off < 256; off <<= 1) {
    int v = (tid >= off) ? sums[tid - off] : 0;
    __syncthreads();
    sums[tid] += v;
    __syncthreads();
  }
  int run = sums[tid] - s;
  for (int i = start; i < end; ++i) {
    o[i] = run;
    cu[i] = run;
    run += d[i];
  }
}

__global__ void k_scatter(const int* __restrict__ edges, int* __restrict__ cursor,
                          int* __restrict__ csr) {
  const int TMAP[4] = {0, 1, 3, 4};
  int c = blockIdx.y;
  int t = TMAP[c];
  int e = blockIdx.x * 256 + threadIdx.x;
  if (e < NEDGE) {
    int src = edges[(size_t)t * 2 * NEDGE + e];
    int dst = edges[(size_t)t * 2 * NEDGE + NEDGE + e];
    int slot = atomicAdd(&cursor[c * NNODES + dst], 1);
    csr[(size_t)c * NEDGE + slot] = src;
  }
}

// Canonicalize CSR: in-place insertion sort of each row's src list, so the
// downstream accumulation order is identical every launch (atomic scatter
// order is timing-dependent).
__global__ void k_sort(const int* __restrict__ offs, const int* __restrict__ rend,
                       int* __restrict__ csr) {
  int c = blockIdx.y;
  int i = blockIdx.x * 256 + threadIdx.x;
  if (i >= NNODES) return;
  int* row = csr + (size_t)c * NEDGE;
  int s = offs[c * NNODES + i];
  int e = rend[c * NNODES + i];
  for (int j = s + 1; j < e; ++j) {
    int key = row[j];
    int k = j - 1;
    while (k >= s && row[k] > key) {
      row[k + 1] = row[k];
      --k;
    }
    row[k + 1] = key;
  }
}

// ---------------------------------------------------------------- aggregation
// Column-split: 2 waves per dst row, each covers a 256-col half (f16x4/lane).
struct AggSlot {
  const f16* dst;
  const f16* dst2;   // nullable: base = relu(dst+dst2)
  const f16* src1;
  const int* offs1;
  const int* rend1;
  const int* csr1;
  f16* out1;
  const f16* src2;   // nullable: second list sharing base
  const int* offs2;
  const int* rend2;
  const int* csr2;
  f16* out2;
};
struct AggBatch { AggSlot s[3]; };

__device__ __forceinline__ void agg_list(const f16* __restrict__ hs,
                                         const int* __restrict__ cs,
                                         int e, int e1, int col,
                                         const float* __restrict__ base,
                                         f16* __restrict__ outp) {
  float acc[4];
#pragma unroll
  for (int q = 0; q < 4; ++q) acc[q] = base[q];
  for (; e + 3 < e1; e += 4) {
    int s0 = cs[e], s1 = cs[e + 1], s2 = cs[e + 2], s3 = cs[e + 3];
    f16x4 u0 = *(const f16x4*)(hs + (size_t)s0 * HDIM + col);
    f16x4 u1 = *(const f16x4*)(hs + (size_t)s1 * HDIM + col);
    f16x4 u2 = *(const f16x4*)(hs + (size_t)s2 * HDIM + col);
    f16x4 u3 = *(const f16x4*)(hs + (size_t)s3 * HDIM + col);
#pragma unroll
    for (int q = 0; q < 4; ++q)
      acc[q] += ((float)u0[q] + (float)u1[q]) + ((float)u2[q] + (float)u3[q]);
  }
  for (; e < e1; ++e) {
    int s0 = cs[e];
    f16x4 u0 = *(const f16x4*)(hs + (size_t)s0 * HDIM + col);
#pragma unroll
    for (int q = 0; q < 4; ++q) acc[q] += (float)u0[q];
  }
  f16x4 o;
#pragma unroll
  for (int q = 0; q < 4; ++q) o[q] = (f16)acc[q];
  *(f16x4*)outp = o;
}

__global__ __launch_bounds__(256) void k_agg(AggBatch ab) {
  const AggSlot sl = ab.s[blockIdx.y];
  int w = threadIdx.x >> 6;
  int i = blockIdx.x * 2 + (w >> 1);          // dst row
  int lane = threadIdx.x & 63;
  int col = (w & 1) * 256 + lane * 4;         // column within row
  const size_t off = (size_t)i * HDIM + col;
  float base[4];
  f16x4 v = *(const f16x4*)(sl.dst + off);
  if (sl.dst2) {
    f16x4 v2 = *(const f16x4*)(sl.dst2 + off);
#pragma unroll
    for (int q = 0; q < 4; ++q) base[q] = fmaxf((float)v[q] + (float)v2[q], 0.f);
  } else {
#pragma unroll
    for (int q = 0; q < 4; ++q) base[q] = (float)v[q];
  }
  agg_list(sl.src1, sl.csr1, sl.offs1[i], sl.rend1[i], col, base, sl.out1 + off);
  if (sl.src2)
    agg_list(sl.src2, sl.csr2, sl.offs2[i], sl.rend2[i], col, base, sl.out2 + off);
}

// ---------------------------------------------------------------- GEMM (C = A @ Bt^T)
// Tile 128(M) x 128(N), BK=32, 256 threads = 4 waves (2x2, each 64x64, 4x4 frags).
// Deterministic double-buffer (R11): one __syncthreads/iter, prefetch issued
// after the barrier so DMA overlaps ds_read+MFMA. 4 blocks/CU.
// XCD-aware swizzle: flat grid 640 blocks/z; g -> mt=(g>>5)*8+(g&7), n=(g>>3)&3.
// Consecutive hw blocks round-robin over 8 XCDs, so this puts an m-tile's 4
// n-siblings on ONE XCD (per-XCD set: 20 m-tiles x 1KB x 128 rows = 2.5MB +
// B 0.5MB < 4MB L2) -> A fetched once per XCD, 3 L2-hit reuses inside the
// one-iteration prefetch window. Pure perf heuristic; correctness-neutral.
struct GemmBatch {
  const f16* A[6];
  const f16* B[6];
  const float* bias[6];
  const float* bias2[6];
  void* D[6];
  int flags[6];
  int Kz[6];
  int lda[6];
  int ldd[6];
};

__global__ __launch_bounds__(256, 4) void k_gemm(GemmBatch gb, int M) {
  __shared__ __align__(16) char smem[32768];  // A: 2x8KB @0; B: 2x8KB @16384; epilogue reuses [0,17408)
  const int z = blockIdx.z;
  const int g = blockIdx.x;
  const int mt = (g >> 5) * 8 + (g & 7);
  if (mt * 128 >= M) return;                  // padded tail (uniform per block)
  const int m0 = mt * 128;
  const int n0 = ((g >> 3) & 3) * 128;
  const f16* __restrict__ A = gb.A[z];
  const f16* __restrict__ Bt = gb.B[z];
  const int flags = gb.flags[z];
  const int K = gb.Kz[z];
  const int lda = gb.lda[z];
  const int ldd = gb.ldd[z];
  const int tid = threadIdx.x;
  const int lane = tid & 63;
  const int wave = tid >> 6;
  const int wm = wave & 1, wn = wave >> 1;
  const int fr = lane & 15, fq = lane >> 4;
  const int r0 = tid >> 2;         // staging row within 64-row half
  const int co = (tid & 3) * 8;    // staging col offset in elements

  const f16* gA0 = A + (size_t)min(m0 + r0, M - 1) * lda + co;
  const f16* gA1 = A + (size_t)min(m0 + 64 + r0, M - 1) * lda + co;
  const f16* gB0 = Bt + (size_t)(n0 + r0) * K + co;
  const f16* gB1 = Bt + (size_t)(n0 + 64 + r0) * K + co;

  f32x4 acc[4][4];
#pragma unroll
  for (int a = 0; a < 4; ++a)
#pragma unroll
    for (int b = 0; b < 4; ++b) acc[a][b] = (f32x4){0.f, 0.f, 0.f, 0.f};

  auto stage = [&](int b, int kk) {
    char* bufA = smem + b * 8192;
    char* bufB = smem + 16384 + b * 8192;
    async_lds16(gA0 + kk, bufA + wave * 1024);
    async_lds16(gA1 + kk, bufA + 4096 + wave * 1024);
    async_lds16(gB0 + kk, bufB + wave * 1024);
    async_lds16(gB1 + kk, bufB + 4096 + wave * 1024);
  };

  const int nb = K >> 5;
  stage(0, 0);
  for (int i = 0; i < nb; ++i) {
    const int cur = i & 1;
    // Drains this wave's outstanding DMA (buffer `cur` now complete) and all
    // prior ds_reads (buffer `cur^1` now free) before anyone re-stages it.
    __syncthreads();
    if (i + 1 < nb) stage(cur ^ 1, (i + 1) << 5);  // DMA overlaps compute below
    const f16* lA = (const f16*)(smem + cur * 8192);
    const f16* lB = (const f16*)(smem + 16384 + cur * 8192);
    f16x8 af[4], bf[4];
#pragma unroll
    for (int t = 0; t < 4; ++t)
      af[t] = *(const f16x8*)&lA[(wm * 64 + t * 16 + fr) * 32 + fq * 8];
#pragma unroll
    for (int t = 0; t < 4; ++t)
      bf[t] = *(const f16x8*)&lB[(wn * 64 + t * 16 + fr) * 32 + fq * 8];
#pragma unroll
    for (int mt2 = 0; mt2 < 4; ++mt2)
#pragma unroll
      for (int nt = 0; nt < 4; ++nt)
        acc[mt2][nt] = __builtin_amdgcn_mfma_f32_16x16x32_f16(af[mt2], bf[nt], acc[mt2][nt], 0, 0, 0);
  }
  __syncthreads();  // all LDS reads done before epilogue reuses the buffers

  const float* __restrict__ bias = gb.bias[z];
  const float* __restrict__ bias2 = gb.bias2[z];

  // f16 out via LDS bounce: 2 passes of 64 rows, padded stride 136 f16
  f16* tile = (f16*)smem;
#pragma unroll
  for (int pass = 0; pass < 2; ++pass) {
    if (wm == pass) {
#pragma unroll
      for (int nt = 0; nt < 4; ++nt) {
        const int cl = wn * 64 + nt * 16 + fr;
        float bv = bias[n0 + cl];
        if (bias2) bv += bias2[n0 + cl];
#pragma unroll
        for (int mt2 = 0; mt2 < 4; ++mt2) {
#pragma unroll
          for (int r = 0; r < 4; ++r) {
            float v = acc[mt2][nt][r] + bv;
            if (flags & 1) v = fmaxf(v, 0.f);
            tile[(mt2 * 16 + fq * 4 + r) * 136 + cl] = (f16)v;
          }
        }
      }
    }
    __syncthreads();
#pragma unroll
    for (int q = 0; q < 4; ++q) {
      int idx = q * 256 + tid;
      int row = idx >> 4;
      int c8 = idx & 15;
      int grow = m0 + pass * 64 + row;
      f16x8 val = *(const f16x8*)&tile[row * 136 + c8 * 8];
      if (grow < M)
        *(f16x8*)((f16*)gb.D[z] + (size_t)grow * ldd + n0 + c8 * 8) = val;
    }
    __syncthreads();
  }
}

// ---------------------------------------------------------------- head
// y = relu(o) @ W_out + b_out   (o f16 [20000,512])
__global__ __launch_bounds__(256) void k_head(const f16* __restrict__ o,
                                              const float* __restrict__ Wout,
                                              const float* __restrict__ bout,
                                              float* __restrict__ y) {
  int i = blockIdx.x * 4 + (threadIdx.x >> 6);
  int lane = threadIdx.x & 63;
  f16x8 a = *(const f16x8*)(o + (size_t)i * HDIM + lane * 8);
  const float4* w = (const float4*)(Wout + lane * 8);
  float4 w0 = w[0], w1 = w[1];
  float wv[8] = {w0.x, w0.y, w0.z, w0.w, w1.x, w1.y, w1.z, w1.w};
  float s = 0.f;
#pragma unroll
  for (int q = 0; q < 8; ++q)
    s += fmaxf((float)a[q], 0.f) * wv[q];
#pragma unroll
  for (int m = 32; m; m >>= 1) s += __shfl_xor(s, m, 64);
  if (lane == 0) y[i] = s + bout[0];
}

// ---------------------------------------------------------------- launch
extern "C" void kernel_launch(void* const* d_in, const int* in_sizes, int n_in,
                              void* d_out, int out_size, void* d_ws, size_t ws_size,
                              hipStream_t stream) {
  const float* x_all = (const float*)d_in[0];
  const float* W_in = (const float*)d_in[1];
  const float* b_in = (const float*)d_in[2];
  const float* W1 = (const float*)d_in[3];
  const float* b1 = (const float*)d_in[4];
  const float* W2 = (const float*)d_in[5];
  const float* b2 = (const float*)d_in[6];
  const float* W_out = (const float*)d_in[7];
  const float* b_out = (const float*)d_in[8];
  const int* edges = (const int*)d_in[9];

  // ---- workspace carve (~207 MB)
  char* p = (char*)d_ws;
  auto take = [&](size_t bytes) {
    char* r = p;
    p += (bytes + 255) & ~(size_t)255;
    return r;
  };
  f16* xb = (f16*)take((size_t)5 * NNODES * FIN * 2);
  f16* Wint = (f16*)take((size_t)5 * HDIM * FIN * 2);
  f16* W1t = (f16*)take((size_t)6 * HH * 2);
  f16* W2t = (f16*)take((size_t)6 * HH * 2);
  int* deg = (int*)take((size_t)4 * NNODES * 4);
  int* offs = (int*)take((size_t)4 * NNODES * 4);
  int* cursor = (int*)take((size_t)4 * NNODES * 4);
  int* csr = (int*)take((size_t)4 * NEDGE * 4);
  f16* pool = (f16*)take((size_t)9 * SLICE * 2);
  auto P = [&](int s) { return pool + (size_t)s * SLICE; };
  f16* Z0 = P(0);  // [20000][1024] spanning P0,P1 (also reused as Z1 at layer 1)

  // ---- prep (fused) + CSR (+ canonical sort for launch-determinism)
  k_prep<<<27489, 256, 0, stream>>>(x_all, xb, W_in, Wint, W1, W2, W1t, W2t, deg);
  k_hist<<<dim3(625, 4), 256, 0, stream>>>(edges, deg);
  k_scan<<<4, 256, 0, stream>>>(deg, offs, cursor);
  k_scatter<<<dim3(625, 4), 256, 0, stream>>>(edges, cursor, csr);
  k_sort<<<dim3(79, 4), 256, 0, stream>>>(offs, cursor, csr);

  const int GX = 640;  // 160 padded m-tiles x 4 n, XCD-swizzled in-kernel

  // ---- input projection: h0 types {0..4} -> {P0..P4}
  {
    GemmBatch g{};
    for (int t = 0; t < 5; ++t) {
      g.A[t] = xb + (size_t)t * NNODES * FIN;
      g.B[t] = Wint + (size_t)t * HDIM * FIN;
      g.bias[t] = b_in + (size_t)t * HDIM;
      g.D[t] = P(t);
      g.flags[t] = 1;
      g.Kz[t] = FIN; g.lda[t] = FIN; g.ldd[t] = HDIM;
    }
    k_gemm<<<dim3(GX, 1, 5), 256, 0, stream>>>(g, NNODES);
  }

  // ---- layer 0 aggregations:
  // slot0 (dst h0[0]=P0): t1 src P1 -> P5; t4 src P3 -> P6
  // slot1 (dst h0[1]=P1): t0 src P4 -> P7
  // slot2 (dst h0[3]=P3): t3 src P2 -> P8
  {
    AggBatch a{};
    a.s[0].dst = P(0);
    a.s[0].src1 = P(1); a.s[0].offs1 = offs + 1 * NNODES;
    a.s[0].rend1 = cursor + 1 * NNODES; a.s[0].csr1 = csr + (size_t)1 * NEDGE;
    a.s[0].out1 = P(5);
    a.s[0].src2 = P(3); a.s[0].offs2 = offs + 3 * NNODES;
    a.s[0].rend2 = cursor + 3 * NNODES; a.s[0].csr2 = csr + (size_t)3 * NEDGE;
    a.s[0].out2 = P(6);
    a.s[1].dst = P(1);
    a.s[1].src1 = P(4); a.s[1].offs1 = offs + 0 * NNODES;
    a.s[1].rend1 = cursor + 0 * NNODES; a.s[1].csr1 = csr + (size_t)0 * NEDGE;
    a.s[1].out1 = P(7);
    a.s[2].dst = P(3);
    a.s[2].src1 = P(2); a.s[2].offs1 = offs + 2 * NNODES;
    a.s[2].rend1 = cursor + 2 * NNODES; a.s[2].csr1 = csr + (size_t)2 * NEDGE;
    a.s[2].out1 = P(8);
    k_agg<<<dim3(10000, 3), 256, 0, stream>>>(a);
  }

  // ---- layer 0 MLP1 (z=4): t1: P5->Z0c0; t4: P6->Z0c512; t0: P7->P2; t3: P8->P3
  {
    GemmBatch g{};
    g.A[0] = P(5); g.B[0] = W1t + 1 * HH; g.bias[0] = b1 + 1 * HDIM;
    g.D[0] = Z0; g.flags[0] = 1; g.Kz[0] = 512; g.lda[0] = 512; g.ldd[0] = 1024;
    g.A[1] = P(6); g.B[1] = W1t + 3 * HH; g.bias[1] = b1 + 4 * HDIM;
    g.D[1] = Z0 + 512; g.flags[1] = 1; g.Kz[1] = 512; g.lda[1] = 512; g.ldd[1] = 1024;
    g.A[2] = P(7); g.B[2] = W1t + 0 * HH; g.bias[2] = b1 + 0 * HDIM;
    g.D[2] = P(2); g.flags[2] = 1; g.Kz[2] = 512; g.lda[2] = 512; g.ldd[2] = 512;
    g.A[3] = P(8); g.B[3] = W1t + 2 * HH; g.bias[3] = b1 + 3 * HDIM;
    g.D[3] = P(3); g.flags[3] = 1; g.Kz[3] = 512; g.lda[3] = 512; g.ldd[3] = 512;
    k_gemm<<<dim3(GX, 1, 4), 256, 0, stream>>>(g, NNODES);
  }

  // ---- layer 0 MLP2 (z=3):
  // z0: h1_t0 = relu(Z0 @ cat[W2(0,1);W2(0,4)] + b2a+b2b) -> P4 (K=1024)
  // z1: h1_t1 = relu(P2 @ W2(0,0) + b2) -> P5
  // z2: h1_t3 = relu(P3 @ W2(0,3) + b2) -> P6
  {
    GemmBatch g{};
    g.A[0] = Z0; g.B[0] = W2t + 2 * HH; g.bias[0] = b2 + 1 * HDIM;
    g.bias2[0] = b2 + 4 * HDIM; g.D[0] = P(4);
    g.flags[0] = 1; g.Kz[0] = 1024; g.lda[0] = 1024; g.ldd[0] = 512;
    g.A[1] = P(2); g.B[1] = W2t + 0 * HH; g.bias[1] = b2 + 0 * HDIM;
    g.D[1] = P(5); g.flags[1] = 1; g.Kz[1] = 512; g.lda[1] = 512; g.ldd[1] = 512;
    g.A[2] = P(3); g.B[2] = W2t + 1 * HH; g.bias[2] = b2 + 3 * HDIM;
    g.D[2] = P(6); g.flags[2] = 1; g.Kz[2] = 512; g.lda[2] = 512; g.ldd[2] = 512;
    k_gemm<<<dim3(GX, 1, 3), 256, 0, stream>>>(g, NNODES);
  }

  // ---- layer 1 aggregation: base = P4 (h1_t0); src P5 (t1 csr) -> P7; src P6 (t4 csr) -> P8
  {
    AggBatch a{};
    a.s[0].dst = P(4);
    a.s[0].src1 = P(5); a.s[0].offs1 = offs + 1 * NNODES;
    a.s[0].rend1 = cursor + 1 * NNODES; a.s[0].csr1 = csr + (size_t)1 * NEDGE;
    a.s[0].out1 = P(7);
    a.s[0].src2 = P(6); a.s[0].offs2 = offs + 3 * NNODES;
    a.s[0].rend2 = cursor + 3 * NNODES; a.s[0].csr2 = csr + (size_t)3 * NEDGE;
    a.s[0].out2 = P(8);
    k_agg<<<dim3(10000, 1), 256, 0, stream>>>(a);
  }

  // ---- layer 1 MLP1 (z=2): P7 -> Z1 col0; P8 -> Z1 col512   (Z1 = [P0|P1], Z0 dead)
  f16* Z1 = Z0;
  {
    GemmBatch g{};
    g.A[0] = P(7); g.B[0] = W1t + 4 * HH; g.bias[0] = b1 + 7 * HDIM;
    g.D[0] = Z1; g.flags[0] = 1; g.Kz[0] = 512; g.lda[0] = 512; g.ldd[0] = 1024;
    g.A[1] = P(8); g.B[1] = W1t + 5 * HH; g.bias[1] = b1 + 10 * HDIM;
    g.D[1] = Z1 + 512; g.flags[1] = 1; g.Kz[1] = 512; g.lda[1] = 512; g.ldd[1] = 1024;
    k_gemm<<<dim3(GX, 1, 2), 256, 0, stream>>>(g, NNODES);
  }

  // ---- layer 1 MLP2 (z=1, K=1024 concat): o = Z1 @ cat[W2(1,1);W2(1,4)] + b2a+b2b -> P2 (f16)
  {
    GemmBatch g{};
    g.A[0] = Z1; g.B[0] = W2t + 4 * HH; g.bias[0] = b2 + 7 * HDIM;
    g.bias2[0] = b2 + 10 * HDIM; g.D[0] = P(2);
    g.flags[0] = 0; g.Kz[0] = 1024; g.lda[0] = 1024; g.ldd[0] = 512;
    k_gemm<<<dim3(GX, 1, 1), 256, 0, stream>>>(g, NNODES);
  }

  // ---- head
  k_head<<<5000, 256, 0, stream>>>(P(2), W_out, b_out, (float*)d_out);
}